// Round 1
// baseline (320.592 us; speedup 1.0000x reference)
//
#include <hip/hip_runtime.h>

// Frame-wise E^H D E exact NDFT via separable phasors as two complex GEMMs on
// fp16 matrix cores (fp32 accumulate).
// v2 changes vs prior best (276.5us):
//  - adj_gemm: 4-way k-split (grid z=4, atomicAdd epilogue on zeroed out) to lift
//    occupancy from 1 block/CU; conflict-free Ts build (row=tid>>3, col=tid&7);
//    g relaid out [t][c][k] (32B contiguous build loads); build loads issued
//    BEFORE the MFMA phase (latency hidden under MFMA).
//  - fwd_gemm: 512 thr, 8 waves x (8mf x 1nf) -> 64 acc VGPRs (was 128);
//    __launch_bounds__(512,4); A-stage + B fragment prefetched 1 chunk ahead.
//  - Tables retiled so all B/Ey fragment reads are sector-contiguous:
//      ExC [t][kt16][xc8][kp128][xq16], EyC same with y, ExT [t][kc64][x128][kq32],
//      srcB [t][c][xc8][y128][xq16].
//  - prep: direct per-element sincos (2 kernels, each store-coalesced) + tiny
//    ktraj transpose; replaces the 128-block recurrence kernel with scattered stores.

#define NT 16
#define NK 2048
#define NXY 128
#define NC 8

typedef _Float16 f16x8 __attribute__((ext_vector_type(8)));
typedef float f32x4 __attribute__((ext_vector_type(4)));

union F8 { f16x8 h; uint u[4]; };

#define MFMA16(a, b, c) __builtin_amdgcn_mfma_f32_16x16x32_f16((a), (b), (c), 0, 0, 0)

__device__ __forceinline__ uint pack2h(float a, float b) {
    union { _Float16 h[2]; uint u; } p;
    p.h[0] = (_Float16)a; p.h[1] = (_Float16)b;
    return p.u;
}
__device__ __forceinline__ float2 unpack2h(uint v) {
    union { uint u; _Float16 h[2]; } p;
    p.u = v;
    return make_float2((float)p.h[0], (float)p.h[1]);
}
__device__ __forceinline__ uint rot16(uint v) { return (v >> 16) | (v << 16); }

// ---------------------------------------------------------------------------
// ktrajT[d][t][k] = ktraj[d][k][t]  (so phasor kernels read k-contiguous)
// ---------------------------------------------------------------------------
__global__ __launch_bounds__(256) void prep_ktraj(const float* __restrict__ ktraj,
                                                  float* __restrict__ ktrajT) {
    const int idx = blockIdx.x * 256 + threadIdx.x;          // < 2*NK*NT = 65536
    const int t = idx & 15, k = (idx >> 4) & (NK - 1), d = idx >> 15;
    ktrajT[((size_t)d * NT + t) * NK + k] = ktraj[((size_t)d * NK + k) * NT + t];
}

// ---------------------------------------------------------------------------
// ExC[t][kt][xc][kp][xq], EyC[t][kt][yc][kp][yq]; value exp(-i*k*(x-64)).
// Lanes = x -> 64B-sector coalesced stores. k broadcast within half-block.
// ---------------------------------------------------------------------------
__global__ __launch_bounds__(256) void prep_phasA(const float* __restrict__ ktrajT,
                                                  uint* __restrict__ ExC,
                                                  uint* __restrict__ EyC) {
    const int t = blockIdx.x;
    const int k = blockIdx.y * 2 + (threadIdx.x >> 7);
    const int x = threadIdx.x & 127;
    const float kx = ktrajT[(size_t)t * NK + k];
    const float ky = ktrajT[(size_t)(NT + t) * NK + k];
    const float xm = (float)(x - 64);
    const size_t off = ((size_t)(t * 16 + (k >> 7)) * 8 + (x >> 4)) * 2048 +
                       (size_t)(k & 127) * 16 + (x & 15);
    float s, c;
    __sincosf(-kx * xm, &s, &c);
    ExC[off] = pack2h(c, s);
    __sincosf(-ky * xm, &s, &c);
    EyC[off] = pack2h(c, s);
}

// ---------------------------------------------------------------------------
// ExT[t][kc][x][kq]; lanes = k -> 128B-run coalesced stores.
// ---------------------------------------------------------------------------
__global__ __launch_bounds__(256) void prep_phasB(const float* __restrict__ ktrajT,
                                                  uint* __restrict__ ExT) {
    const int t = blockIdx.x, x = blockIdx.y;
    const int k = blockIdx.z * 256 + threadIdx.x;
    const float kx = ktrajT[(size_t)t * NK + k];
    float s, c;
    __sincosf(-kx * (float)(x - 64), &s, &c);
    ExT[((size_t)(t * 64 + (k >> 5)) * 128 + x) * 32 + (k & 31)] = pack2h(c, s);
}

// ---------------------------------------------------------------------------
// srcB[t][c][xc][y][xq] = (smap[c,x,y] * img[x,y,t]) packed complex fp16
// ---------------------------------------------------------------------------
__global__ __launch_bounds__(256) void prep_src(const float* __restrict__ xin,
                                                const float* __restrict__ csmap,
                                                uint* __restrict__ srcB) {
    const int idx = blockIdx.x * 256 + threadIdx.x;   // < 16*8*128*128
    const int x = idx & 127, y = (idx >> 7) & 127, c = (idx >> 14) & 7, t = idx >> 17;
    const float ir = xin[(size_t)(x * NXY + y) * NT + t];
    const float ii = xin[(size_t)NXY * NXY * NT + (size_t)(x * NXY + y) * NT + t];
    const float sr = csmap[(size_t)c * 2 * NXY * NXY + x * NXY + y];
    const float si = csmap[(size_t)c * 2 * NXY * NXY + NXY * NXY + x * NXY + y];
    srcB[((size_t)((t * NC + c) * 8 + (x >> 4)) * NXY + y) * 16 + (x & 15)] =
        pack2h(sr * ir - si * ii, sr * ii + si * ir);
}

// ---------------------------------------------------------------------------
// fwd_gemm: block = (t, c, ktile of 128 kpoints), 512 thr (8 waves).
// C1[y=128, kp=128] over K'=256 (x r/i-interleaved), 8 chunks of 16 x-dwords.
// Per wave: 8mf x 1nf -> 16 f32x4 accumulators (64 VGPR).  A-stage and B
// fragment prefetched one chunk ahead into registers.
// ---------------------------------------------------------------------------
__global__ __launch_bounds__(512, 4) void fwd_gemm(const uint* __restrict__ ExC,
                                                   const uint* __restrict__ EyC,
                                                   const uint* __restrict__ srcB,
                                                   const float* __restrict__ dcomp,
                                                   float2* __restrict__ g) {
    const int t = blockIdx.x, c = blockIdx.y, kt = blockIdx.z;
    const int tid = threadIdx.x, lane = tid & 63, ws = tid >> 6;
    const int quad = lane >> 4, l15 = lane & 15;
    const int kp_local = ws * 16 + l15;

    __shared__ __align__(16) _Float16 As[2][128][40];   // 32 K'-halves + 8 pad

    f32x4 accr[8], acci[8];
#pragma unroll
    for (int mf = 0; mf < 8; ++mf) { accr[mf] = (f32x4)0.0f; acci[mf] = (f32x4)0.0f; }

    const uint* srcT = srcB + (size_t)(t * NC + c) * 8 * 2048;   // [xc][y][xq]
    const uint* exB  = ExC + (size_t)(t * 16 + kt) * 16384;      // [xc][kp][xq]
    const int sy = tid >> 2, sx8 = (tid & 3) * 8;                // As row / half-col
    const int soff = sy * 16 + (tid & 3) * 4;                    // dwords within chunk tile

    // prologue: stage chunk 0, preload B(ch0)
    {
        F8 vA = *(const F8*)(srcT + soff);
        *(F8*)&As[0][sy][sx8] = vA;
    }
    __syncthreads();
    F8 Bf = *(const F8*)(exB + kp_local * 16 + quad * 4);

    for (int ch = 0; ch < 8; ++ch) {
        const int buf = ch & 1;
        F8 vAn, BfN;
        if (ch < 7) {                                   // issue next-chunk loads early
            vAn = *(const F8*)(srcT + (ch + 1) * 2048 + soff);
            BfN = *(const F8*)(exB + (ch + 1) * 2048 + kp_local * 16 + quad * 4);
        }
#pragma unroll
        for (int mf = 0; mf < 8; ++mf) {
            F8 Ap = *(const F8*)&As[buf][mf * 16 + l15][quad * 8];
            F8 Ar, Ai;
#pragma unroll
            for (int d = 0; d < 4; ++d) {
                Ar.u[d] = Ap.u[d] ^ 0x80000000u;        // (sR, -sI)
                Ai.u[d] = rot16(Ap.u[d]);               // (sI,  sR)
            }
            accr[mf] = MFMA16(Ar.h, Bf.h, accr[mf]);
            acci[mf] = MFMA16(Ai.h, Bf.h, acci[mf]);
        }
        if (ch < 7) {
            *(F8*)&As[buf ^ 1][sy][sx8] = vAn;
            Bf = BfN;
        }
        __syncthreads();
    }

    // epilogue: y-reduction with Ey, then g[t][c][k]
    const uint* eyB = EyC + (size_t)(t * 16 + kt) * 16384;
    const int kpoint = kt * 128 + kp_local;
    float kdr = 0.f, kdi = 0.f;
#pragma unroll
    for (int mf = 0; mf < 8; ++mf) {
        F8 e4 = *(const F8*)(eyB + mf * 2048 + kp_local * 16 + quad * 4);
#pragma unroll
        for (int rr = 0; rr < 4; ++rr) {
            float2 ey = unpack2h(e4.u[rr]);
            float cr = accr[mf][rr], ci = acci[mf][rr];
            kdr += ey.x * cr - ey.y * ci;
            kdi += ey.x * ci + ey.y * cr;
        }
    }
    kdr += __shfl_xor(kdr, 16); kdr += __shfl_xor(kdr, 32);
    kdi += __shfl_xor(kdi, 16); kdi += __shfl_xor(kdi, 32);
    if (lane < 16) {
        float w = dcomp[(size_t)kpoint * NT + t] * (1.0f / 16384.0f);
        g[(size_t)(t * NC + c) * NK + kpoint] = make_float2(kdr * w, kdi * w);
    }
}

// ---------------------------------------------------------------------------
// adj_gemm: block = (t, ytile of 8 y, kz of 4 k-segments), 512 thr (8 waves).
// C3[m=(yloc*8+c)=64, x=128] over K'=1024 per block (512 kpoints), 16 chunks
// of 32 kpoints.  Build: row=tid>>3, col=tid&7 -> 128B-contiguous LDS writes
// per 8 lanes (conflict-free); g[t][c][k] -> 32B contiguous loads; build loads
// issued before the MFMA phase.  Epilogue: conj(smap) combine + atomicAdd.
// ---------------------------------------------------------------------------
__global__ __launch_bounds__(512, 4) void adj_gemm(const uint* __restrict__ ExT,
                                                   const uint* __restrict__ EyC,
                                                   const float2* __restrict__ g,
                                                   const float* __restrict__ csmap,
                                                   float* __restrict__ out) {
    const int t = blockIdx.x, yt = blockIdx.y, kz = blockIdx.z, ybase = yt * 8;
    const int tid = threadIdx.x, lane = tid & 63, ws = tid >> 6;
    const int quad = lane >> 4, l15 = lane & 15;
    const int x = ws * 16 + l15;

    __shared__ __align__(16) _Float16 Ts[2][64][72];    // 64 K'-halves + 8 pad

    f32x4 accr[4], acci[4];
#pragma unroll
    for (int mf = 0; mf < 4; ++mf) { accr[mf] = (f32x4)0.0f; acci[mf] = (f32x4)0.0f; }

    const int br = tid >> 3, u = tid & 7;               // build row (m), kp sub-chunk
    const int by = ybase + (br >> 3), bc = br & 7;

    const float2* gRow = g + (size_t)(t * NC + bc) * NK;
    const uint* eyT = EyC + (size_t)t * 262144;         // + kt*16384
    const int ybank = (by >> 4) * 2048 + (by & 15);
    const uint* exB = ExT + ((size_t)t * 64 + kz * 16) * 4096;   // + ch*4096

    float4 ga, gb; uint ev0, ev1, ev2, ev3;
    {   // build loads, chunk 0
        const int kpg = kz * 512 + u * 4;
        ga = *(const float4*)(gRow + kpg);
        gb = *(const float4*)(gRow + kpg + 2);
        const uint* ey = eyT + (size_t)(kpg >> 7) * 16384 + (size_t)(kpg & 127) * 16 + ybank;
        ev0 = ey[0]; ev1 = ey[16]; ev2 = ey[32]; ev3 = ey[48];
    }
    {   // pack t2 = conj(Ey)*g, write chunk 0
        F8 w; float2 e;
        e = unpack2h(ev0); w.u[0] = pack2h(e.x*ga.x + e.y*ga.y, e.x*ga.y - e.y*ga.x);
        e = unpack2h(ev1); w.u[1] = pack2h(e.x*ga.z + e.y*ga.w, e.x*ga.w - e.y*ga.z);
        e = unpack2h(ev2); w.u[2] = pack2h(e.x*gb.x + e.y*gb.y, e.x*gb.y - e.y*gb.x);
        e = unpack2h(ev3); w.u[3] = pack2h(e.x*gb.z + e.y*gb.w, e.x*gb.w - e.y*gb.z);
        *(F8*)&Ts[0][br][u * 8] = w;
    }
    __syncthreads();

    for (int ch = 0; ch < 16; ++ch) {
        const int buf = ch & 1;
        if (ch < 15) {                                  // issue next-chunk build loads
            const int kpg = kz * 512 + (ch + 1) * 32 + u * 4;
            ga = *(const float4*)(gRow + kpg);
            gb = *(const float4*)(gRow + kpg + 2);
            const uint* ey = eyT + (size_t)(kpg >> 7) * 16384 + (size_t)(kpg & 127) * 16 + ybank;
            ev0 = ey[0]; ev1 = ey[16]; ev2 = ey[32]; ev3 = ey[48];
        }
        const uint* exCh = exB + (size_t)ch * 4096 + x * 32;
#pragma unroll
        for (int ks = 0; ks < 2; ++ks) {
            F8 Bf = *(const F8*)(exCh + ks * 16 + quad * 4);
#pragma unroll
            for (int mf = 0; mf < 4; ++mf) {
                F8 Ap = *(const F8*)&Ts[buf][mf * 16 + l15][ks * 32 + quad * 8];
                F8 Ai;
#pragma unroll
                for (int d = 0; d < 4; ++d) Ai.u[d] = rot16(Ap.u[d]) ^ 0x80000000u; // (t2I, -t2R)
                accr[mf] = MFMA16(Ap.h, Bf.h, accr[mf]);
                acci[mf] = MFMA16(Ai.h, Bf.h, acci[mf]);
            }
        }
        if (ch < 15) {                                  // pack + write after MFMAs
            F8 w; float2 e;
            e = unpack2h(ev0); w.u[0] = pack2h(e.x*ga.x + e.y*ga.y, e.x*ga.y - e.y*ga.x);
            e = unpack2h(ev1); w.u[1] = pack2h(e.x*ga.z + e.y*ga.w, e.x*ga.w - e.y*ga.z);
            e = unpack2h(ev2); w.u[2] = pack2h(e.x*gb.x + e.y*gb.y, e.x*gb.y - e.y*gb.x);
            e = unpack2h(ev3); w.u[3] = pack2h(e.x*gb.z + e.y*gb.w, e.x*gb.w - e.y*gb.z);
            *(F8*)&Ts[buf ^ 1][br][u * 8] = w;
        }
        __syncthreads();
    }

    // epilogue: coil-combine with conj(smap), atomicAdd into zeroed out
#pragma unroll
    for (int mf = 0; mf < 4; ++mf) {
        const int y = ybase + 2 * mf + (quad >> 1);
        float or_ = 0.f, oi_ = 0.f;
#pragma unroll
        for (int rr = 0; rr < 4; ++rr) {
            int c = 4 * (quad & 1) + rr;
            float sr = csmap[(size_t)c * 2 * NXY * NXY + x * NXY + y];
            float si = csmap[(size_t)c * 2 * NXY * NXY + NXY * NXY + x * NXY + y];
            float xr = accr[mf][rr], xi = acci[mf][rr];
            or_ += sr * xr + si * xi;
            oi_ += sr * xi - si * xr;
        }
        or_ += __shfl_xor(or_, 16);
        oi_ += __shfl_xor(oi_, 16);
        if ((lane & 16) == 0) {
            atomicAdd(out + (size_t)(x * NXY + y) * NT + t, or_);
            atomicAdd(out + (size_t)NXY * NXY * NT + (size_t)(x * NXY + y) * NT + t, oi_);
        }
    }
}

// ---------------------------------------------------------------------------
extern "C" void kernel_launch(void* const* d_in, const int* in_sizes, int n_in,
                              void* d_out, int out_size, void* d_ws, size_t ws_size,
                              hipStream_t stream) {
    const float* xin   = (const float*)d_in[0];  // (2,128,128,16)
    const float* ktraj = (const float*)d_in[1];  // (2,2048,16)
    const float* csmap = (const float*)d_in[2];  // (8,2,128,128)
    const float* dcomp = (const float*)d_in[3];  // (2048,16)
    float* out = (float*)d_out;                  // (2,128,128,16)

    // ws layout (dwords of packed complex fp16, then fp32): ~61 MB total
    const size_t TBL = (size_t)NT * NK * NXY;            // 4.19M dwords per table
    uint* ExC  = (uint*)d_ws;                            // [t][kt][xc][kp][xq]
    uint* ExT  = ExC + TBL;                              // [t][kc][x][kq]
    uint* EyC  = ExT + TBL;                              // [t][kt][yc][kp][yq]
    uint* srcB = EyC + TBL;                              // [t][c][xc][y][xq]
    float2* g  = (float2*)(srcB + (size_t)NT * NC * NXY * NXY);  // [t][c][k]
    float* ktrajT = (float*)(g + (size_t)NT * NC * NK);  // [d][t][k]

    hipMemsetAsync(d_out, 0, (size_t)out_size, stream);  // adj accumulates atomically
    prep_ktraj<<<dim3(2 * NK * NT / 256), 256, 0, stream>>>(ktraj, ktrajT);
    prep_phasA<<<dim3(NT, NK / 2), 256, 0, stream>>>(ktrajT, ExC, EyC);
    prep_phasB<<<dim3(NT, NXY, NK / 256), 256, 0, stream>>>(ktrajT, ExT);
    prep_src<<<dim3((NT * NC * NXY * NXY) / 256), 256, 0, stream>>>(xin, csmap, srcB);
    fwd_gemm<<<dim3(NT, NC, NK / 128), 512, 0, stream>>>(ExC, EyC, srcB, dcomp, g);
    adj_gemm<<<dim3(NT, NXY / 8, 4), 512, 0, stream>>>(ExT, EyC, g, csmap, out);
}